// Round 7
// baseline (125.961 us; speedup 1.0000x reference)
//
#include <hip/hip_runtime.h>
#include <hip/hip_bf16.h>
#include <stdint.h>

#define BATCH 4096
#define N_TOT 8192
#define D_DIM 256
#define SHIFT 150.0f
#define SQRT2 1.41421356237309515f

typedef float f32x4 __attribute__((ext_vector_type(4)));
typedef long lx2 __attribute__((ext_vector_type(2)));

// global -> LDS direct copy, 16B per lane. LDS dest is wave-uniform base;
// HW scatters lane*16B.
__device__ __forceinline__ void gl_lds16(const void* g, void* l) {
  __builtin_amdgcn_global_load_lds(
      (const __attribute__((address_space(1))) void*)(uintptr_t)g,
      (__attribute__((address_space(3))) void*)(uint32_t)(uintptr_t)l,
      16, 0, 0);
}

// Fused: fp8 e4m3 convert (x sqrt2) written in fragment-transposed row layout,
// + positive-pair fp32 dot partials. Row layout T: 16B chunk c = quad*4+ks2
// holds the A/B fragments for MFMA steps ks=2*ks2,2*ks2+1 of that quad, i.e.
// global k-bytes {64*ks2+quad*8+0..7, 64*ks2+32+quad*8+0..7}. Lane l holds
// k=4l..4l+3 -> one 4B word at T offset f(l) below.
__global__ void k_prep(const float* __restrict__ hi, const float* __restrict__ hj,
                       uint8_t* __restrict__ hb8T, float* __restrict__ posPartial) {
  const int wave = threadIdx.x >> 6, lane = threadIdx.x & 63;
  const int r = blockIdx.x * 4 + wave;
  const size_t off = (size_t)r * D_DIM + lane * 4;
  float4 a = *(const float4*)(hi + off);
  float4 b = *(const float4*)(hj + off);

  int wa = __builtin_amdgcn_cvt_pk_fp8_f32(a.x * SQRT2, a.y * SQRT2, 0, false);
  wa = __builtin_amdgcn_cvt_pk_fp8_f32(a.z * SQRT2, a.w * SQRT2, wa, true);
  int wb = __builtin_amdgcn_cvt_pk_fp8_f32(b.x * SQRT2, b.y * SQRT2, 0, false);
  wb = __builtin_amdgcn_cvt_pk_fp8_f32(b.z * SQRT2, b.w * SQRT2, wb, true);

  // T offset: quad=(l>>1)&3, ks2=l>>4, kodd=(l>>3)&1, inner=(l&1)*4
  const int toff = ((lane >> 1) & 3) * 64 + (lane >> 4) * 16 +
                   ((lane >> 3) & 1) * 8 + (lane & 1) * 4;
  *(int*)(hb8T + (size_t)r * 256 + toff) = wa;
  *(int*)(hb8T + (size_t)(BATCH + r) * 256 + toff) = wb;

  float d = a.x * b.x + a.y * b.y + a.z * b.z + a.w * b.w;
#pragma unroll
  for (int o = 32; o >= 1; o >>= 1) d += __shfl_xor(d, o);
  __shared__ float ps[4];
  if (lane == 0) ps[wave] = d;
  __syncthreads();
  if (threadIdx.x == 0) posPartial[blockIdx.x] = ps[0] + ps[1] + ps[2] + ps[3];
}

// Upper-triangular 128x128 tiles of sim = hb.hb^T (fp8), whole-K staged once
// (64KB LDS, one barrier). Fragment reads are ds_read_b128 at XOR-swizzled
// 16B slots -> uniform 4 lanes/chunk = b128 phase minimum, zero conflicts.
// Epilogue: exp(sim-SHIFT) -> per-wave row/col sums stored (PLAIN stores, no
// atomics) into private slices of Zpart[128][8192]:
//   rows -> slice 2*bj+wn, cols (off-diag) -> slice 2*bi+wm.
// Coverage: slice (b,h) rows [0,128(b+1)) from tiles (bi<=b,b), cols
// [128(b+1),8192) from tiles (b,bj>b) -- exact partition, no init needed.
__global__ __launch_bounds__(256, 2) void k_gemm(const uint8_t* __restrict__ hb8T,
                                                 float* __restrict__ Zpart) {
  const int t = blockIdx.x;
  int bj = (int)((sqrtf(8.0f * (float)t + 1.0f) - 1.0f) * 0.5f);
  while ((bj + 1) * (bj + 2) / 2 <= t) ++bj;
  while (bj * (bj + 1) / 2 > t) --bj;
  const int bi = t - bj * (bj + 1) / 2;
  const int rBase = bi * 128;
  const int cBase = bj * 128;
  const bool diag = (bi == bj);

  __shared__ __align__(16) uint8_t As[128 * 256];
  __shared__ __align__(16) uint8_t Bs[128 * 256];
  const int lane = threadIdx.x & 63;
  const int wave = threadIdx.x >> 6;

  // staging: waves 0,1 -> As halves; 2,3 -> Bs halves. LDS[row][slot s] =
  // T[row][s ^ (row&15)] via global-side swizzle (scatter is fixed lane*16B).
  {
    const int half = wave & 1;
    const int gbase = (wave < 2 ? rBase : cBase) + half * 64;
    uint8_t* lbase = (wave < 2 ? As : Bs) + half * 64 * 256;
    const int rowOff = lane >> 4, c16 = lane & 15;
#pragma unroll
    for (int i = 0; i < 16; ++i) {
      const int r = i * 4 + rowOff;
      const uint8_t* src = hb8T + (size_t)(gbase + r) * 256 + ((c16 ^ (r & 15)) * 16);
      gl_lds16(src, lbase + i * 1024 + lane * 16);
    }
  }
  __syncthreads();  // the one drain

  const int wm = wave >> 1, wn = wave & 1;
  const int quad = lane >> 4, l16 = lane & 15;

  f32x4 acc[4][4];
#pragma unroll
  for (int i = 0; i < 4; ++i)
#pragma unroll
    for (int j = 0; j < 4; ++j) acc[i][j] = (f32x4){0.f, 0.f, 0.f, 0.f};

#pragma unroll
  for (int ks2 = 0; ks2 < 4; ++ks2) {  // each = 2 MFMA K-steps, no barriers
    const int slot = ((quad * 4 + ks2) ^ l16) * 16;
    lx2 a[4], b[4];
#pragma unroll
    for (int mt = 0; mt < 4; ++mt)
      a[mt] = *(const lx2*)(As + (wm * 64 + mt * 16 + l16) * 256 + slot);
#pragma unroll
    for (int nt = 0; nt < 4; ++nt)
      b[nt] = *(const lx2*)(Bs + (wn * 64 + nt * 16 + l16) * 256 + slot);
#pragma unroll
    for (int mt = 0; mt < 4; ++mt)
#pragma unroll
      for (int nt = 0; nt < 4; ++nt) {
        acc[mt][nt] = __builtin_amdgcn_mfma_f32_16x16x32_fp8_fp8(a[mt].x, b[nt].x,
                                                                 acc[mt][nt], 0, 0, 0);
        acc[mt][nt] = __builtin_amdgcn_mfma_f32_16x16x32_fp8_fp8(a[mt].y, b[nt].y,
                                                                 acc[mt][nt], 0, 0, 0);
      }
  }

  // epilogue: e = exp(sim - SHIFT); C/D map: col=l16, row=quad*4+reg
  const int rW = rBase + wm * 64 + quad * 4;
  const int cW = cBase + wn * 64 + l16;
  float* rowSlice = Zpart + (size_t)(2 * bj + wn) * N_TOT;
  float* colSlice = Zpart + (size_t)(2 * bi + wm) * N_TOT;
  float colAcc[4] = {0.f, 0.f, 0.f, 0.f};
#pragma unroll
  for (int mt = 0; mt < 4; ++mt) {
#pragma unroll
    for (int rg = 0; rg < 4; ++rg) {
      const int rr = rW + mt * 16 + rg;
      float s = 0.f;
#pragma unroll
      for (int nt = 0; nt < 4; ++nt) {
        float e = __expf(acc[mt][nt][rg] - SHIFT);
        if (diag && (rr == cW + nt * 16)) e = 0.f;  // mask self-similarity
        s += e;
        colAcc[nt] += e;
      }
      s += __shfl_xor(s, 1);
      s += __shfl_xor(s, 2);
      s += __shfl_xor(s, 4);
      s += __shfl_xor(s, 8);
      if (l16 == 0) rowSlice[rr] = s;  // plain store, slice-private
    }
  }
  if (!diag) {
#pragma unroll
    for (int nt = 0; nt < 4; ++nt) {
      float c = colAcc[nt];
      c += __shfl_xor(c, 16);
      c += __shfl_xor(c, 32);
      if (lane < 16) colSlice[cW + nt * 16] = c;  // 16 contiguous floats
    }
  }
}

// 32 blocks x 256: Z_r = sum over 128 slices; lsePartial[blk] = sum log(Z_r)
__global__ void k_reduce(const float* __restrict__ Zpart,
                         float* __restrict__ lsePartial) {
  const int r = blockIdx.x * 256 + threadIdx.x;
  float z = 0.f;
#pragma unroll
  for (int s = 0; s < 128; ++s) z += Zpart[(size_t)s * N_TOT + r];
  float v = __logf(z);
#pragma unroll
  for (int o = 32; o >= 1; o >>= 1) v += __shfl_xor(v, o);
  __shared__ float ps[4];
  const int wave = threadIdx.x >> 6, lane = threadIdx.x & 63;
  if (lane == 0) ps[wave] = v;
  __syncthreads();
  if (threadIdx.x == 0) lsePartial[blockIdx.x] = ps[0] + ps[1] + ps[2] + ps[3];
}

// One block: loss = sum(lsePartial)/N + SHIFT - sum(posPartial)/2048
__global__ void k_finish(const float* __restrict__ lsePartial,
                         const float* __restrict__ posPartial,
                         float* __restrict__ out) {
  const int t = threadIdx.x;  // 0..1023
  float sl = (t < 32) ? lsePartial[t] : 0.f;
  float sp = posPartial[t];
#pragma unroll
  for (int o = 32; o >= 1; o >>= 1) {
    sl += __shfl_xor(sl, o);
    sp += __shfl_xor(sp, o);
  }
  __shared__ float pl[16], pp[16];
  const int wave = t >> 6, lane = t & 63;
  if (lane == 0) { pl[wave] = sl; pp[wave] = sp; }
  __syncthreads();
  if (t == 0) {
    float L = 0.f, P = 0.f;
    for (int i = 0; i < 16; ++i) { L += pl[i]; P += pp[i]; }
    out[0] = L / (float)N_TOT + SHIFT - P / 2048.0f;
  }
}

extern "C" void kernel_launch(void* const* d_in, const int* in_sizes, int n_in,
                              void* d_out, int out_size, void* d_ws, size_t ws_size,
                              hipStream_t stream) {
  const float* hi = (const float*)d_in[0];
  const float* hj = (const float*)d_in[1];
  float* out = (float*)d_out;

  uint8_t* hb8T = (uint8_t*)d_ws;                                    // 2 MB
  float* Zpart = (float*)((char*)d_ws + (size_t)N_TOT * D_DIM);      // 4 MB
  float* posPartial = Zpart + (size_t)128 * N_TOT;                   // 4 KB
  float* lsePartial = posPartial + 1024;                             // 128 B

  k_prep<<<1024, 256, 0, stream>>>(hi, hj, hb8T, posPartial);
  k_gemm<<<2080, 256, 0, stream>>>(hb8T, Zpart);
  k_reduce<<<32, 256, 0, stream>>>(Zpart, lsePartial);
  k_finish<<<1, 1024, 0, stream>>>(lsePartial, posPartial, out);
}

// Round 8
// 108.437 us; speedup vs baseline: 1.1616x; 1.1616x over previous
//
#include <hip/hip_runtime.h>
#include <hip/hip_bf16.h>
#include <stdint.h>

#define BATCH 4096
#define N_TOT 8192
#define D_DIM 256
#define SHIFT 150.0f
#define SQRT2 1.41421356237309515f

typedef float f32x4 __attribute__((ext_vector_type(4)));
typedef long lx2 __attribute__((ext_vector_type(2)));

// global -> LDS direct copy, 16B per lane. LDS dest is wave-uniform base;
// HW scatters lane*16B.
__device__ __forceinline__ void gl_lds16(const void* g, void* l) {
  __builtin_amdgcn_global_load_lds(
      (const __attribute__((address_space(1))) void*)(uintptr_t)g,
      (__attribute__((address_space(3))) void*)(uint32_t)(uintptr_t)l,
      16, 0, 0);
}

// Fused: fp8 e4m3 convert (x sqrt2) in fragment-transposed row layout T,
// positive-pair fp32 dot partials, Zrow zero-init.
// T: 16B chunk c = quad*4+ks2 holds k-bytes {64ks2+32kodd+quad*8+0..7}.
__global__ void k_prep(const float* __restrict__ hi, const float* __restrict__ hj,
                       uint8_t* __restrict__ hb8T, float* __restrict__ Zrow,
                       float* __restrict__ posPartial) {
  const int wave = threadIdx.x >> 6, lane = threadIdx.x & 63;
  const int r = blockIdx.x * 4 + wave;
  const size_t off = (size_t)r * D_DIM + lane * 4;
  float4 a = *(const float4*)(hi + off);
  float4 b = *(const float4*)(hj + off);

  int wa = __builtin_amdgcn_cvt_pk_fp8_f32(a.x * SQRT2, a.y * SQRT2, 0, false);
  wa = __builtin_amdgcn_cvt_pk_fp8_f32(a.z * SQRT2, a.w * SQRT2, wa, true);
  int wb = __builtin_amdgcn_cvt_pk_fp8_f32(b.x * SQRT2, b.y * SQRT2, 0, false);
  wb = __builtin_amdgcn_cvt_pk_fp8_f32(b.z * SQRT2, b.w * SQRT2, wb, true);

  const int toff = ((lane >> 1) & 3) * 64 + (lane >> 4) * 16 +
                   ((lane >> 3) & 1) * 8 + (lane & 1) * 4;
  *(int*)(hb8T + (size_t)r * 256 + toff) = wa;
  *(int*)(hb8T + (size_t)(BATCH + r) * 256 + toff) = wb;

  float d = a.x * b.x + a.y * b.y + a.z * b.z + a.w * b.w;
#pragma unroll
  for (int o = 32; o >= 1; o >>= 1) d += __shfl_xor(d, o);
  __shared__ float ps[4];
  if (lane == 0) ps[wave] = d;
  if (threadIdx.x < 8) Zrow[blockIdx.x * 8 + threadIdx.x] = 0.f;
  __syncthreads();
  if (threadIdx.x == 0) posPartial[blockIdx.x] = ps[0] + ps[1] + ps[2] + ps[3];
}

// Multi-tile blocks: block (bi = id&63, s = id>>6) stages As (128 rows) ONCE,
// then walks col-tiles bj = bi+s, bi+s+8, ... (upper triangle), re-staging
// only Bs (32KB) per tile. Next-Bs loads issue before the epilogue so the
// drain hides behind exp/shfl/atomics. 64KB LDS -> 2 blocks/CU (TLP).
// Whole-K resident (BK=256): one drain per tile, no K-loop barriers.
// Fragment reads: ds_read_b128 at XOR-swizzled 16B slots (uniform 4
// lanes/slot). Epilogue: exp(sim-SHIFT); row sums via l16-shfl + atomicAdd;
// col sums (bj>bi only, symmetry) via quad-shfl + atomicAdd.
__global__ __launch_bounds__(256, 2) void k_gemm(const uint8_t* __restrict__ hb8T,
                                                 float* __restrict__ Zrow) {
  const int bi = blockIdx.x & 63;
  const int s = blockIdx.x >> 6;
  if (bi + s >= 64) return;  // uniform early-exit, no barriers crossed

  __shared__ __align__(16) uint8_t As[128 * 256];
  __shared__ __align__(16) uint8_t Bs[128 * 256];
  const int lane = threadIdx.x & 63;
  const int wave = threadIdx.x >> 6;
  const int rowOff = lane >> 4, c16 = lane & 15;
  const int rBase = bi * 128;

  // stage As once: 32 issues x 1KB, 8 per wave. LDS[r][slot c] = T[r][c^(r&15)]
#pragma unroll
  for (int i = 0; i < 8; ++i) {
    const int idx = wave * 8 + i;
    const int r = idx * 4 + rowOff;
    gl_lds16(hb8T + (size_t)(rBase + r) * 256 + ((c16 ^ (r & 15)) * 16),
             As + idx * 1024 + lane * 16);
  }
  // stage first Bs
  {
    const int cBase0 = (bi + s) * 128;
#pragma unroll
    for (int i = 0; i < 8; ++i) {
      const int idx = wave * 8 + i;
      const int r = idx * 4 + rowOff;
      gl_lds16(hb8T + (size_t)(cBase0 + r) * 256 + ((c16 ^ (r & 15)) * 16),
               Bs + idx * 1024 + lane * 16);
    }
  }

  const int wm = wave >> 1, wn = wave & 1;
  const int quad = lane >> 4, l16 = lane & 15;

  for (int bj = bi + s; bj < 64; bj += 8) {
    __syncthreads();  // drain staged As(first pass)+Bs(bj)

    f32x4 acc[4][4];
#pragma unroll
    for (int i = 0; i < 4; ++i)
#pragma unroll
      for (int j = 0; j < 4; ++j) acc[i][j] = (f32x4){0.f, 0.f, 0.f, 0.f};

#pragma unroll
    for (int ks2 = 0; ks2 < 4; ++ks2) {  // 2 MFMA K-steps each, no barriers
      const int slot = ((quad * 4 + ks2) ^ l16) * 16;
      lx2 a[4], b[4];
#pragma unroll
      for (int mt = 0; mt < 4; ++mt)
        a[mt] = *(const lx2*)(As + (wm * 64 + mt * 16 + l16) * 256 + slot);
#pragma unroll
      for (int nt = 0; nt < 4; ++nt)
        b[nt] = *(const lx2*)(Bs + (wn * 64 + nt * 16 + l16) * 256 + slot);
#pragma unroll
      for (int mt = 0; mt < 4; ++mt)
#pragma unroll
        for (int nt = 0; nt < 4; ++nt) {
          acc[mt][nt] = __builtin_amdgcn_mfma_f32_16x16x32_fp8_fp8(
              a[mt].x, b[nt].x, acc[mt][nt], 0, 0, 0);
          acc[mt][nt] = __builtin_amdgcn_mfma_f32_16x16x32_fp8_fp8(
              a[mt].y, b[nt].y, acc[mt][nt], 0, 0, 0);
        }
    }

    __syncthreads();  // all waves done reading Bs

    // prefetch next Bs NOW; its flight hides behind the epilogue below
    if (bj + 8 < 64) {
      const int cBaseN = (bj + 8) * 128;
#pragma unroll
      for (int i = 0; i < 8; ++i) {
        const int idx = wave * 8 + i;
        const int r = idx * 4 + rowOff;
        gl_lds16(hb8T + (size_t)(cBaseN + r) * 256 + ((c16 ^ (r & 15)) * 16),
                 Bs + idx * 1024 + lane * 16);
      }
    }

    // epilogue: e = exp(sim - SHIFT); C/D map: col=l16, row=quad*4+reg
    const bool diag = (bj == bi);
    const int cBase = bj * 128;
    const int rW = rBase + wm * 64 + quad * 4;
    const int cW = cBase + wn * 64 + l16;
    float colAcc[4] = {0.f, 0.f, 0.f, 0.f};
#pragma unroll
    for (int mt = 0; mt < 4; ++mt) {
#pragma unroll
      for (int rg = 0; rg < 4; ++rg) {
        const int rr = rW + mt * 16 + rg;
        float sv = 0.f;
#pragma unroll
        for (int nt = 0; nt < 4; ++nt) {
          float e = __expf(acc[mt][nt][rg] - SHIFT);
          if (diag && (rr == cW + nt * 16)) e = 0.f;  // mask self-similarity
          sv += e;
          colAcc[nt] += e;
        }
        sv += __shfl_xor(sv, 1);
        sv += __shfl_xor(sv, 2);
        sv += __shfl_xor(sv, 4);
        sv += __shfl_xor(sv, 8);
        if (l16 == 0) atomicAdd(&Zrow[rr], sv);
      }
    }
    if (!diag) {
#pragma unroll
      for (int nt = 0; nt < 4; ++nt) {
        float c = colAcc[nt];
        c += __shfl_xor(c, 16);
        c += __shfl_xor(c, 32);
        if (lane < 16) atomicAdd(&Zrow[cW + nt * 16], c);
      }
    }
  }
}

// One block: loss = mean(log Z + SHIFT) - sum(dot)/2048
__global__ void k_finish(const float* __restrict__ Zrow,
                         const float* __restrict__ posPartial,
                         float* __restrict__ out) {
  const int t = threadIdx.x;  // 0..1023
  float4 z0 = *(const float4*)(Zrow + t * 8);
  float4 z1 = *(const float4*)(Zrow + t * 8 + 4);
  float sl = __logf(z0.x) + __logf(z0.y) + __logf(z0.z) + __logf(z0.w) +
             __logf(z1.x) + __logf(z1.y) + __logf(z1.z) + __logf(z1.w);
  float sp = posPartial[t];
#pragma unroll
  for (int o = 32; o >= 1; o >>= 1) {
    sl += __shfl_xor(sl, o);
    sp += __shfl_xor(sp, o);
  }
  __shared__ float pl[16], pp[16];
  const int wave = t >> 6, lane = t & 63;
  if (lane == 0) { pl[wave] = sl; pp[wave] = sp; }
  __syncthreads();
  if (t == 0) {
    float L = 0.f, P = 0.f;
    for (int i = 0; i < 16; ++i) { L += pl[i]; P += pp[i]; }
    out[0] = L / (float)N_TOT + SHIFT - P / 2048.0f;
  }
}

extern "C" void kernel_launch(void* const* d_in, const int* in_sizes, int n_in,
                              void* d_out, int out_size, void* d_ws, size_t ws_size,
                              hipStream_t stream) {
  const float* hi = (const float*)d_in[0];
  const float* hj = (const float*)d_in[1];
  float* out = (float*)d_out;

  uint8_t* hb8T = (uint8_t*)d_ws;                                  // 2 MB
  float* Zrow = (float*)((char*)d_ws + (size_t)N_TOT * D_DIM);     // 32 KB
  float* posPartial = Zrow + N_TOT;                                // 4 KB

  k_prep<<<1024, 256, 0, stream>>>(hi, hj, hb8T, Zrow, posPartial);
  k_gemm<<<512, 256, 0, stream>>>(hb8T, Zrow);
  k_finish<<<1, 1024, 0, stream>>>(Zrow, posPartial, out);
}